// Round 4
// baseline (413.112 us; speedup 1.0000x reference)
//
#include <hip/hip_runtime.h>
#include <hip/hip_bf16.h>

#define F_IN 128

typedef short bf16x8 __attribute__((ext_vector_type(8)));
typedef short bf16x4 __attribute__((ext_vector_type(4)));
typedef float f32x4  __attribute__((ext_vector_type(4)));

// ---------------- CSR construction ----------------

__global__ void k_zero(int* __restrict__ p, int n) {
  int i = blockIdx.x * blockDim.x + threadIdx.x;
  if (i < n) p[i] = 0;
}

__global__ void k_count(const int* __restrict__ dst, int* __restrict__ cnt, int E) {
  int i = blockIdx.x * blockDim.x + threadIdx.x;
  if (i < E) atomicAdd(&cnt[dst[i]], 1);
}

__global__ void k_scan1(const int* __restrict__ cnt, int* __restrict__ rp,
                        int* __restrict__ bsum, float* __restrict__ dis,
                        int* __restrict__ fill, int n) {
  int tid = threadIdx.x;
  int i = blockIdx.x * 256 + tid;
  int v = (i < n) ? cnt[i] : 0;
  int orig = v;
  int lane = tid & 63;
  #pragma unroll
  for (int d = 1; d < 64; d <<= 1) {
    int t = __shfl_up(v, d);
    if (lane >= d) v += t;
  }
  __shared__ int wsum[4];
  int wid = tid >> 6;
  if (lane == 63) wsum[wid] = v;
  __syncthreads();
  int off = 0;
  for (int w = 0; w < wid; ++w) off += wsum[w];
  int incl = v + off;
  if (i < n) {
    rp[i]   = incl - orig;
    dis[i]  = rsqrtf(1.0f + (float)orig);
    fill[i] = 0;
  }
  if (tid == 255) bsum[blockIdx.x] = incl;
}

__global__ void k_scan2(int* __restrict__ bsum, int nb) {
  __shared__ int s[1024];
  int tid = threadIdx.x;
  int v = (tid < nb) ? bsum[tid] : 0;
  s[tid] = v;
  __syncthreads();
  for (int d = 1; d < 1024; d <<= 1) {
    int t = (tid >= d) ? s[tid - d] : 0;
    __syncthreads();
    s[tid] += t;
    __syncthreads();
  }
  if (tid < nb) bsum[tid] = s[tid] - v;
}

__global__ void k_scan3(int* __restrict__ rp, const int* __restrict__ bsum, int n, int E) {
  int i = blockIdx.x * blockDim.x + threadIdx.x;
  if (i < n) rp[i] += bsum[i >> 8];
  if (i == 0) rp[n] = E;
}

// packed (col, weight) per edge
__global__ void k_fill_csr(const int* __restrict__ src, const int* __restrict__ dst,
                           const int* __restrict__ rp, int* __restrict__ fill,
                           const float* __restrict__ dis,
                           int2* __restrict__ cw, int E) {
  int e = blockIdx.x * blockDim.x + threadIdx.x;
  if (e < E) {
    int s = src[e], d = dst[e];
    int pos = rp[d] + atomicAdd(&fill[d], 1);
    cw[pos] = make_int2(s, __float_as_int(dis[s] * dis[d]));
  }
}

// ---------------- gather+convert building_x[l2g] -> compact bf16 [n,128] ----------------

__global__ void k_tobf16(const float* __restrict__ X, const int* __restrict__ l2g,
                         ushort* __restrict__ out, int n) {
  int i = blockIdx.x * blockDim.x + threadIdx.x;   // one thread per 4 elems
  if (i >= n * 32) return;
  int row = i >> 5, c4 = (i & 31) * 4;
  int g = l2g[row];
  float4 v = *(const float4*)(X + (size_t)g * 128 + c4);
  ushort o[4];
  __hip_bfloat16 h;
  h = __float2bfloat16(v.x); o[0] = *(ushort*)&h;
  h = __float2bfloat16(v.y); o[1] = *(ushort*)&h;
  h = __float2bfloat16(v.z); o[2] = *(ushort*)&h;
  h = __float2bfloat16(v.w); o[3] = *(ushort*)&h;
  uint2 pk;
  pk.x = (uint)o[0] | ((uint)o[1] << 16);
  pk.y = (uint)o[2] | ((uint)o[3] << 16);
  *(uint2*)(out + (size_t)row * 128 + c4) = pk;
}

// ---------------- aggregation, bf16 table, 4 edges in flight per wave ----------------

template <bool BIASRELU>
__global__ void k_aggb(const ushort* __restrict__ X, const int* __restrict__ rp,
                       const int2* __restrict__ cw, const float* __restrict__ dis,
                       const float* __restrict__ bias, ushort* __restrict__ outp, int n) {
  int wavei = (int)((blockIdx.x * (size_t)blockDim.x + threadIdx.x) >> 6);
  int lane = threadIdx.x & 63;
  if (wavei >= n) return;
  int q = lane >> 4, ln = lane & 15;
  float d2 = dis[wavei]; d2 = d2 * d2;
  int e0 = rp[wavei], deg = rp[wavei + 1] - e0;
  float acc[8];
  #pragma unroll
  for (int j = 0; j < 8; ++j) acc[j] = 0.0f;

  for (int t0 = -1; t0 < deg; t0 += 4) {
    int t = t0 + q;
    int s; float w;
    if (t < 0)        { s = wavei; w = d2; }
    else if (t < deg) { int2 c = cw[e0 + t]; s = c.x; w = __int_as_float(c.y); }
    else              { s = wavei; w = 0.0f; }
    uint4 r = *(const uint4*)(X + (size_t)s * 128 + ln * 8);
    uint u[4] = {r.x, r.y, r.z, r.w};
    #pragma unroll
    for (int tt = 0; tt < 4; ++tt) {
      float lo = __uint_as_float((u[tt] & 0xffffu) << 16);
      float hi = __uint_as_float(u[tt] & 0xffff0000u);
      acc[2 * tt]     = fmaf(w, lo, acc[2 * tt]);
      acc[2 * tt + 1] = fmaf(w, hi, acc[2 * tt + 1]);
    }
  }
  #pragma unroll
  for (int j = 0; j < 8; ++j) {
    acc[j] += __shfl_xor(acc[j], 16);
    acc[j] += __shfl_xor(acc[j], 32);
  }
  if (q == 0) {
    if (BIASRELU) {
      float4 b0 = *(const float4*)(bias + ln * 8);
      float4 b1 = *(const float4*)(bias + ln * 8 + 4);
      float bb[8] = {b0.x, b0.y, b0.z, b0.w, b1.x, b1.y, b1.z, b1.w};
      #pragma unroll
      for (int j = 0; j < 8; ++j) acc[j] = fmaxf(acc[j] + bb[j], 0.0f);
    }
    ushort o[8];
    #pragma unroll
    for (int j = 0; j < 8; ++j) {
      __hip_bfloat16 h = __float2bfloat16(acc[j]);
      o[j] = *(ushort*)&h;
    }
    uint4 pk;
    pk.x = (uint)o[0] | ((uint)o[1] << 16);
    pk.y = (uint)o[2] | ((uint)o[3] << 16);
    pk.z = (uint)o[4] | ((uint)o[5] << 16);
    pk.w = (uint)o[6] | ((uint)o[7] << 16);
    *(uint4*)(outp + (size_t)wavei * 128 + ln * 8) = pk;
  }
}

// ---------------- W -> fragment-major bf16 repack ----------------
// lane l holds W[k = kt*32 + (l>>4)*4 + (j&3) + 16*(j>>2)][col = nt*16 + (l&15)]

template <int KT, int NT>
__global__ void k_prep_w(const float* __restrict__ W, ushort* __restrict__ WF) {
  int tid = blockIdx.x * 256 + threadIdx.x;
  if (tid >= KT * NT * 64) return;
  int l  = tid & 63;
  int nt = (tid >> 6) % NT;
  int kt = tid / (64 * NT);
  int colc = nt * 16 + (l & 15);
  int kbase = kt * 32 + (l >> 4) * 4;
  ushort v[8];
  #pragma unroll
  for (int j = 0; j < 8; ++j) {
    int k = kbase + (j & 3) + 16 * (j >> 2);
    __hip_bfloat16 h = __float2bfloat16(W[(size_t)k * (NT * 16) + colc]);
    v[j] = *(ushort*)&h;
  }
  uint4 pk;
  pk.x = (uint)v[0] | ((uint)v[1] << 16);
  pk.y = (uint)v[2] | ((uint)v[3] << 16);
  pk.z = (uint)v[4] | ((uint)v[5] << 16);
  pk.w = (uint)v[6] | ((uint)v[7] << 16);
  *(uint4*)(WF + (size_t)tid * 8) = pk;
}

// ---------------- MFMA GEMM (swapped operands): D = (X@W)^T per tile ----------------
// mfma(A=WF, B=Xfrag): lane&15 = X-row, hi*4+reg = 4 consecutive output features
// -> packed 8B bf16 (or 16B f32) epilogue stores.

template <int KT, int NT, bool OUTBF16, bool BIASRELU>
__global__ __launch_bounds__(256) void k_gemm_mfma(const ushort* __restrict__ A,
                                                   const ushort* __restrict__ WF,
                                                   const float* __restrict__ bias,
                                                   void* __restrict__ Cout, int n) {
  constexpr int K = KT * 32;
  constexpr int N = NT * 16;
  constexpr int CPR = K / 8;
  __shared__ short lds[64 * CPR * 8];

  int tid = threadIdx.x;
  int r0 = blockIdx.x * 64;

  #pragma unroll
  for (int p = 0; p < (64 * CPR) / 256; ++p) {
    int idx = p * 256 + tid;
    int row = idx / CPR, c = idx % CPR;
    uint4 v = make_uint4(0u, 0u, 0u, 0u);
    if (r0 + row < n) v = *(const uint4*)(A + (size_t)(r0 + row) * K + c * 8);
    *(uint4*)(&lds[row * CPR * 8 + ((c ^ (row & 15))) * 8]) = v;
  }
  __syncthreads();

  int l  = tid & 63;
  int wv = tid >> 6;
  int hi = l >> 4;
  int rowl = wv * 16 + (l & 15);
  int sw = rowl & 15;

  // X fragments: lane l holds X[row=l&15][k=(l>>4)*4 + (j&3) + 16*(j>>2)] per k-tile
  bf16x8 xfrag[KT];
  #pragma unroll
  for (int kt = 0; kt < KT; ++kt) {
    int c0 = kt * 4 + (hi >> 1);
    int within = (hi & 1) * 4;
    bf16x4 lo = *(const bf16x4*)(&lds[rowl * CPR * 8 + (c0 ^ sw) * 8 + within]);
    bf16x4 hx = *(const bf16x4*)(&lds[rowl * CPR * 8 + ((c0 + 2) ^ sw) * 8 + within]);
    bf16x8 a;
    a[0] = lo[0]; a[1] = lo[1]; a[2] = lo[2]; a[3] = lo[3];
    a[4] = hx[0]; a[5] = hx[1]; a[6] = hx[2]; a[7] = hx[3];
    xfrag[kt] = a;
  }

  f32x4 acc[NT];
  #pragma unroll
  for (int nt = 0; nt < NT; ++nt) acc[nt] = f32x4{0.f, 0.f, 0.f, 0.f};

  #pragma unroll
  for (int nt = 0; nt < NT; ++nt) {
    #pragma unroll
    for (int kt = 0; kt < KT; ++kt) {
      bf16x8 b = *(const bf16x8*)(WF + ((size_t)(kt * NT + nt) * 64 + l) * 8);
      // swapped: A-slot = W fragment, B-slot = X fragment -> D=(X@W)^T tile
      acc[nt] = __builtin_amdgcn_mfma_f32_16x16x32_bf16(b, xfrag[kt], acc[nt], 0, 0, 0);
    }
  }

  // epilogue: lane writes 4 consecutive features of ONE row per n-tile
  int grow = r0 + wv * 16 + (l & 15);
  if (grow < n) {
    #pragma unroll
    for (int nt = 0; nt < NT; ++nt) {
      int f0 = nt * 16 + hi * 4;
      float v0 = acc[nt][0], v1 = acc[nt][1], v2 = acc[nt][2], v3 = acc[nt][3];
      if (BIASRELU) {
        float4 bb = *(const float4*)(bias + f0);
        v0 = fmaxf(v0 + bb.x, 0.0f);
        v1 = fmaxf(v1 + bb.y, 0.0f);
        v2 = fmaxf(v2 + bb.z, 0.0f);
        v3 = fmaxf(v3 + bb.w, 0.0f);
      }
      if (OUTBF16) {
        ushort o[4];
        __hip_bfloat16 h;
        h = __float2bfloat16(v0); o[0] = *(ushort*)&h;
        h = __float2bfloat16(v1); o[1] = *(ushort*)&h;
        h = __float2bfloat16(v2); o[2] = *(ushort*)&h;
        h = __float2bfloat16(v3); o[3] = *(ushort*)&h;
        uint2 pk;
        pk.x = (uint)o[0] | ((uint)o[1] << 16);
        pk.y = (uint)o[2] | ((uint)o[3] << 16);
        *(uint2*)((ushort*)Cout + (size_t)grow * N + f0) = pk;
      } else {
        f32x4 pk = {v0, v1, v2, v3};
        *(f32x4*)((float*)Cout + (size_t)grow * N + f0) = pk;
      }
    }
  }
}

// ---------------- GEMM3: bf16 [n,128] @ [128,2] -> [n,2], one wave per row ----------------

__global__ void k_gemm3(const ushort* __restrict__ A, const float* __restrict__ W3,
                        float* __restrict__ h3, int n) {
  int wavei = (int)((blockIdx.x * (size_t)blockDim.x + threadIdx.x) >> 6);
  int lane = threadIdx.x & 63;
  if (wavei >= n) return;
  uint u = *(const uint*)(A + (size_t)wavei * 128 + lane * 2);
  float x0 = __uint_as_float((u & 0xffffu) << 16);
  float x1 = __uint_as_float(u & 0xffff0000u);
  int k0 = lane * 2;
  float a0 = x0 * W3[k0 * 2 + 0] + x1 * W3[k0 * 2 + 2];
  float a1 = x0 * W3[k0 * 2 + 1] + x1 * W3[k0 * 2 + 3];
  #pragma unroll
  for (int d = 32; d >= 1; d >>= 1) {
    a0 += __shfl_xor(a0, d);
    a1 += __shfl_xor(a1, d);
  }
  if (lane == 0) {
    h3[(size_t)wavei * 2 + 0] = a0;
    h3[(size_t)wavei * 2 + 1] = a1;
  }
}

// ---------------- output ----------------

__global__ void k_fillout(float* __restrict__ out, int total) {
  int i = blockIdx.x * blockDim.x + threadIdx.x;
  if (i < total) out[i] = -0.69314718055994531f;
}

__global__ void k_agg3(const float* __restrict__ h3, const int* __restrict__ rp,
                       const int2* __restrict__ cw, const float* __restrict__ dis,
                       const float* __restrict__ b3, const int* __restrict__ l2g,
                       float* __restrict__ out, int n) {
  int i = blockIdx.x * blockDim.x + threadIdx.x;
  if (i >= n) return;
  float d2 = dis[i] * dis[i];
  float a0 = d2 * h3[(size_t)i * 2 + 0];
  float a1 = d2 * h3[(size_t)i * 2 + 1];
  int e0 = rp[i], e1 = rp[i + 1];
  for (int e = e0; e < e1; ++e) {
    int2 c = cw[e];
    float w = __int_as_float(c.y);
    a0 = fmaf(w, h3[(size_t)c.x * 2 + 0], a0);
    a1 = fmaf(w, h3[(size_t)c.x * 2 + 1], a1);
  }
  a0 += b3[0];
  a1 += b3[1];
  float m = fmaxf(a0, a1);
  float lse = m + logf(expf(a0 - m) + expf(a1 - m));
  int g = l2g[i];
  out[(size_t)g * 2 + 0] = a0 - lse;
  out[(size_t)g * 2 + 1] = a1 - lse;
}

// ---------------- launch ----------------

extern "C" void kernel_launch(void* const* d_in, const int* in_sizes, int n_in,
                              void* d_out, int out_size, void* d_ws, size_t ws_size,
                              hipStream_t stream) {
  const float* building_x = (const float*)d_in[0];
  const int*   l2g        = (const int*)d_in[1];
  const int*   esrc       = (const int*)d_in[2];
  const int*   edst       = (const int*)d_in[3];
  const float* W1 = (const float*)d_in[4];
  const float* b1 = (const float*)d_in[5];
  const float* W2 = (const float*)d_in[6];
  const float* b2 = (const float*)d_in[7];
  const float* W3 = (const float*)d_in[8];
  const float* b3 = (const float*)d_in[9];
  float* out = (float*)d_out;

  const int n_total = in_sizes[0] / F_IN;
  const int n_sub   = in_sizes[1];
  const int E       = in_sizes[2];
  const int nb      = (n_sub + 255) / 256;

  // ---- workspace (bf16 128-wide tensors, aliasing across phases) ----
  char* base = (char*)d_ws;
  auto al = [](size_t x) { return (x + 255) & ~(size_t)255; };
  size_t t128 = al((size_t)n_sub * 128 * 2);
  ushort* xsub = (ushort*)base;
  ushort* xt   = (ushort*)(base + t128);
  ushort* x1   = (ushort*)(base + 2 * t128);
  ushort* xt2  = xsub;
  ushort* h2b  = xt;
  size_t off = 2 * t128 + al((size_t)n_sub * 256 * 2);
  auto alloc = [&](size_t bytes) -> void* {
    void* p = base + off;
    off += al(bytes);
    return p;
  };
  float* h3   = (float*)alloc((size_t)n_sub * 2 * 4);
  int*   cnt  = (int*)alloc((size_t)n_sub * 4);
  int*   fill = (int*)alloc((size_t)n_sub * 4);
  int*   rp   = (int*)alloc((size_t)(n_sub + 1) * 4);
  float* dis  = (float*)alloc((size_t)n_sub * 4);
  int2*  cw   = (int2*)alloc((size_t)E * 8);
  int*   bsum = (int*)alloc((size_t)nb * 4);
  ushort* w1f = (ushort*)alloc((size_t)128 * 256 * 2);
  ushort* w2f = (ushort*)alloc((size_t)256 * 128 * 2);
  (void)ws_size; (void)n_in; (void)out_size;

  const int B = 256;

  // weight repack + input bf16 conversion (independent of CSR)
  k_prep_w<4, 16><<<16, 256, 0, stream>>>(W1, w1f);
  k_prep_w<8, 8><<<16, 256, 0, stream>>>(W2, w2f);
  k_tobf16<<<(n_sub * 32 + B - 1) / B, B, 0, stream>>>(building_x, l2g, xsub, n_sub);

  // CSR build
  k_zero<<<(n_sub + B - 1) / B, B, 0, stream>>>(cnt, n_sub);
  k_count<<<(E + B - 1) / B, B, 0, stream>>>(edst, cnt, E);
  k_scan1<<<nb, 256, 0, stream>>>(cnt, rp, bsum, dis, fill, n_sub);
  k_scan2<<<1, 1024, 0, stream>>>(bsum, nb);
  k_scan3<<<(n_sub + B - 1) / B, B, 0, stream>>>(rp, bsum, n_sub, E);
  k_fill_csr<<<(E + B - 1) / B, B, 0, stream>>>(esrc, edst, rp, fill, dis, cw, E);

  int aggBlocks  = (n_sub + 3) / 4;      // 4 waves / 256-thread block
  int gemmBlocks = (n_sub + 63) / 64;

  // Layer 1: aggregate (bf16 gather) -> bf16 xt, MFMA GEMM + bias + relu -> bf16 x1
  k_aggb<false><<<aggBlocks, B, 0, stream>>>(xsub, rp, cw, dis, nullptr, xt, n_sub);
  k_gemm_mfma<4, 16, true, true><<<gemmBlocks, 256, 0, stream>>>(xt, w1f, b1, x1, n_sub);

  // Layer 2: MFMA GEMM (x1 @ W2) -> bf16 h2b, aggregate + bias + relu -> bf16 xt2
  k_gemm_mfma<8, 8, true, false><<<gemmBlocks, 256, 0, stream>>>(x1, w2f, nullptr, h2b, n_sub);
  k_aggb<true><<<aggBlocks, B, 0, stream>>>(h2b, rp, cw, dis, b2, xt2, n_sub);

  // Layer 3: GEMM (2-wide), fill output, aggregate + bias + log_softmax scatter
  k_gemm3<<<aggBlocks, B, 0, stream>>>(xt2, W3, h3, n_sub);
  k_fillout<<<(2 * n_total + B - 1) / B, B, 0, stream>>>(out, 2 * n_total);
  k_agg3<<<(n_sub + B - 1) / B, B, 0, stream>>>(h3, rp, cw, dis, b3, l2g, out, n_sub);
}

// Round 5
// 328.850 us; speedup vs baseline: 1.2562x; 1.2562x over previous
//
#include <hip/hip_runtime.h>
#include <hip/hip_bf16.h>

#define F_IN 128

typedef short bf16x8 __attribute__((ext_vector_type(8)));
typedef short bf16x4 __attribute__((ext_vector_type(4)));
typedef float f32x4  __attribute__((ext_vector_type(4)));

// ---------------- CSR construction ----------------

__global__ void k_zero(int* __restrict__ p, int n) {
  int i = blockIdx.x * blockDim.x + threadIdx.x;
  if (i < n) p[i] = 0;
}

__global__ void k_count(const int* __restrict__ dst, int* __restrict__ cnt, int E) {
  int i = blockIdx.x * blockDim.x + threadIdx.x;
  if (i < E) atomicAdd(&cnt[dst[i]], 1);
}

__global__ void k_scan1(const int* __restrict__ cnt, int* __restrict__ rp,
                        int* __restrict__ bsum, float* __restrict__ dis,
                        int* __restrict__ fill, int n) {
  int tid = threadIdx.x;
  int i = blockIdx.x * 256 + tid;
  int v = (i < n) ? cnt[i] : 0;
  int orig = v;
  int lane = tid & 63;
  #pragma unroll
  for (int d = 1; d < 64; d <<= 1) {
    int t = __shfl_up(v, d);
    if (lane >= d) v += t;
  }
  __shared__ int wsum[4];
  int wid = tid >> 6;
  if (lane == 63) wsum[wid] = v;
  __syncthreads();
  int off = 0;
  for (int w = 0; w < wid; ++w) off += wsum[w];
  int incl = v + off;
  if (i < n) {
    rp[i]   = incl - orig;
    dis[i]  = rsqrtf(1.0f + (float)orig);
    fill[i] = 0;
  }
  if (tid == 255) bsum[blockIdx.x] = incl;
}

__global__ void k_scan2(int* __restrict__ bsum, int nb) {
  __shared__ int s[1024];
  int tid = threadIdx.x;
  int v = (tid < nb) ? bsum[tid] : 0;
  s[tid] = v;
  __syncthreads();
  for (int d = 1; d < 1024; d <<= 1) {
    int t = (tid >= d) ? s[tid - d] : 0;
    __syncthreads();
    s[tid] += t;
    __syncthreads();
  }
  if (tid < nb) bsum[tid] = s[tid] - v;
}

__global__ void k_scan3(int* __restrict__ rp, const int* __restrict__ bsum, int n, int E) {
  int i = blockIdx.x * blockDim.x + threadIdx.x;
  if (i < n) rp[i] += bsum[i >> 8];
  if (i == 0) rp[n] = E;
}

// packed (col, weight) per edge
__global__ void k_fill_csr(const int* __restrict__ src, const int* __restrict__ dst,
                           const int* __restrict__ rp, int* __restrict__ fill,
                           const float* __restrict__ dis,
                           int2* __restrict__ cw, int E) {
  int e = blockIdx.x * blockDim.x + threadIdx.x;
  if (e < E) {
    int s = src[e], d = dst[e];
    int pos = rp[d] + atomicAdd(&fill[d], 1);
    cw[pos] = make_int2(s, __float_as_int(dis[s] * dis[d]));
  }
}

// ---------------- gather+convert building_x[l2g] -> compact bf16 [n,128] ----------------

__global__ void k_tobf16(const float* __restrict__ X, const int* __restrict__ l2g,
                         ushort* __restrict__ out, int n) {
  int i = blockIdx.x * blockDim.x + threadIdx.x;   // one thread per 4 elems
  if (i >= n * 32) return;
  int row = i >> 5, c4 = (i & 31) * 4;
  int g = l2g[row];
  float4 v = *(const float4*)(X + (size_t)g * 128 + c4);
  ushort o[4];
  __hip_bfloat16 h;
  h = __float2bfloat16(v.x); o[0] = *(ushort*)&h;
  h = __float2bfloat16(v.y); o[1] = *(ushort*)&h;
  h = __float2bfloat16(v.z); o[2] = *(ushort*)&h;
  h = __float2bfloat16(v.w); o[3] = *(ushort*)&h;
  uint2 pk;
  pk.x = (uint)o[0] | ((uint)o[1] << 16);
  pk.y = (uint)o[2] | ((uint)o[3] << 16);
  *(uint2*)(out + (size_t)row * 128 + c4) = pk;
}

// ---------------- aggregation, bf16 table, 4 edges in flight per wave ----------------

template <bool BIASRELU>
__global__ void k_aggb(const ushort* __restrict__ X, const int* __restrict__ rp,
                       const int2* __restrict__ cw, const float* __restrict__ dis,
                       const float* __restrict__ bias, ushort* __restrict__ outp, int n) {
  int wavei = (int)((blockIdx.x * (size_t)blockDim.x + threadIdx.x) >> 6);
  int lane = threadIdx.x & 63;
  if (wavei >= n) return;
  int q = lane >> 4, ln = lane & 15;
  float d2 = dis[wavei]; d2 = d2 * d2;
  int e0 = rp[wavei], deg = rp[wavei + 1] - e0;
  float acc[8];
  #pragma unroll
  for (int j = 0; j < 8; ++j) acc[j] = 0.0f;

  for (int t0 = -1; t0 < deg; t0 += 4) {
    int t = t0 + q;
    int s; float w;
    if (t < 0)        { s = wavei; w = d2; }
    else if (t < deg) { int2 c = cw[e0 + t]; s = c.x; w = __int_as_float(c.y); }
    else              { s = wavei; w = 0.0f; }
    uint4 r = *(const uint4*)(X + (size_t)s * 128 + ln * 8);
    uint u[4] = {r.x, r.y, r.z, r.w};
    #pragma unroll
    for (int tt = 0; tt < 4; ++tt) {
      float lo = __uint_as_float((u[tt] & 0xffffu) << 16);
      float hi = __uint_as_float(u[tt] & 0xffff0000u);
      acc[2 * tt]     = fmaf(w, lo, acc[2 * tt]);
      acc[2 * tt + 1] = fmaf(w, hi, acc[2 * tt + 1]);
    }
  }
  #pragma unroll
  for (int j = 0; j < 8; ++j) {
    acc[j] += __shfl_xor(acc[j], 16);
    acc[j] += __shfl_xor(acc[j], 32);
  }
  if (q == 0) {
    if (BIASRELU) {
      float4 b0 = *(const float4*)(bias + ln * 8);
      float4 b1 = *(const float4*)(bias + ln * 8 + 4);
      float bb[8] = {b0.x, b0.y, b0.z, b0.w, b1.x, b1.y, b1.z, b1.w};
      #pragma unroll
      for (int j = 0; j < 8; ++j) acc[j] = fmaxf(acc[j] + bb[j], 0.0f);
    }
    ushort o[8];
    #pragma unroll
    for (int j = 0; j < 8; ++j) {
      __hip_bfloat16 h = __float2bfloat16(acc[j]);
      o[j] = *(ushort*)&h;
    }
    uint4 pk;
    pk.x = (uint)o[0] | ((uint)o[1] << 16);
    pk.y = (uint)o[2] | ((uint)o[3] << 16);
    pk.z = (uint)o[4] | ((uint)o[5] << 16);
    pk.w = (uint)o[6] | ((uint)o[7] << 16);
    *(uint4*)(outp + (size_t)wavei * 128 + ln * 8) = pk;
  }
}

// ---------------- W -> fragment-major bf16 repack ----------------
// lane l holds W[k = kt*32 + (l>>4)*4 + (j&3) + 16*(j>>2)][col = nt*16 + (l&15)]

template <int KT, int NT>
__global__ void k_prep_w(const float* __restrict__ W, ushort* __restrict__ WF) {
  int tid = blockIdx.x * 256 + threadIdx.x;
  if (tid >= KT * NT * 64) return;
  int l  = tid & 63;
  int nt = (tid >> 6) % NT;
  int kt = tid / (64 * NT);
  int colc = nt * 16 + (l & 15);
  int kbase = kt * 32 + (l >> 4) * 4;
  ushort v[8];
  #pragma unroll
  for (int j = 0; j < 8; ++j) {
    int k = kbase + (j & 3) + 16 * (j >> 2);
    __hip_bfloat16 h = __float2bfloat16(W[(size_t)k * (NT * 16) + colc]);
    v[j] = *(ushort*)&h;
  }
  uint4 pk;
  pk.x = (uint)v[0] | ((uint)v[1] << 16);
  pk.y = (uint)v[2] | ((uint)v[3] << 16);
  pk.z = (uint)v[4] | ((uint)v[5] << 16);
  pk.w = (uint)v[6] | ((uint)v[7] << 16);
  *(uint4*)(WF + (size_t)tid * 8) = pk;
}

// ---------------- wave-N-specialized MFMA GEMM ----------------
// Block = 256 threads (4 waves), BM = 128 rows.
// Wave w owns n-tiles [w*NTW, (w+1)*NTW) and PRELOADS its W fragments into
// registers (KT*NTW*4 VGPRs) before the staging barrier. Then loops over the
// 8 row-subtiles reading x-fragments from LDS; acc lives only per-subtile.
// mfma(A=Wfrag, B=Xfrag): lane&15 = X-row, (lane>>4)*4+reg = output features
// -> packed 8B bf16 stores.

template <int KT, int NTW, bool OUTBF16, bool BIASRELU>
__global__ __launch_bounds__(256) void k_gemm_wspec(const ushort* __restrict__ A,
                                                    const ushort* __restrict__ WF,
                                                    const float* __restrict__ bias,
                                                    void* __restrict__ Cout, int n) {
  constexpr int K   = KT * 32;
  constexpr int NT  = NTW * 4;
  constexpr int N   = NT * 16;
  constexpr int CPR = K / 8;                   // 16B chunks per row
  __shared__ short lds[128 * CPR * 8];

  int tid = threadIdx.x;
  int r0 = blockIdx.x * 128;
  int l  = tid & 63;
  int w  = tid >> 6;
  int hi = l >> 4;

  // preload this wave's W-slice into registers (independent of LDS staging)
  bf16x8 wreg[KT * NTW];
  #pragma unroll
  for (int kt = 0; kt < KT; ++kt)
    #pragma unroll
    for (int nt = 0; nt < NTW; ++nt)
      wreg[kt * NTW + nt] =
          *(const bf16x8*)(WF + ((size_t)(kt * NT + w * NTW + nt) * 64 + l) * 8);

  // bias for this wave's feature slice
  float4 bb[NTW];
  if (BIASRELU) {
    #pragma unroll
    for (int nt = 0; nt < NTW; ++nt)
      bb[nt] = *(const float4*)(bias + (w * NTW + nt) * 16 + hi * 4);
  }

  // stage A tile (coalesced 16B loads, XOR-swizzled 16B chunks)
  #pragma unroll
  for (int p = 0; p < (128 * CPR) / 256; ++p) {
    int idx = p * 256 + tid;
    int row = idx / CPR, c = idx % CPR;
    uint4 v = make_uint4(0u, 0u, 0u, 0u);
    if (r0 + row < n) v = *(const uint4*)(A + (size_t)(r0 + row) * K + c * 8);
    *(uint4*)(&lds[row * CPR * 8 + ((c ^ (row & 15))) * 8]) = v;
  }
  __syncthreads();

  int sw = l & 15;
  #pragma unroll
  for (int s = 0; s < 8; ++s) {
    int rowl = s * 16 + (l & 15);
    // X fragments: lane holds X[row=l&15][k=(l>>4)*4 + (j&3) + 16*(j>>2)] per k-tile
    bf16x8 xf[KT];
    #pragma unroll
    for (int kt = 0; kt < KT; ++kt) {
      int c0 = kt * 4 + (hi >> 1);
      int within = (hi & 1) * 4;
      bf16x4 lo = *(const bf16x4*)(&lds[rowl * CPR * 8 + (c0 ^ sw) * 8 + within]);
      bf16x4 hx = *(const bf16x4*)(&lds[rowl * CPR * 8 + ((c0 + 2) ^ sw) * 8 + within]);
      bf16x8 a;
      a[0] = lo[0]; a[1] = lo[1]; a[2] = lo[2]; a[3] = lo[3];
      a[4] = hx[0]; a[5] = hx[1]; a[6] = hx[2]; a[7] = hx[3];
      xf[kt] = a;
    }

    f32x4 acc[NTW];
    #pragma unroll
    for (int nt = 0; nt < NTW; ++nt) acc[nt] = f32x4{0.f, 0.f, 0.f, 0.f};
    #pragma unroll
    for (int nt = 0; nt < NTW; ++nt)
      #pragma unroll
      for (int kt = 0; kt < KT; ++kt)
        acc[nt] = __builtin_amdgcn_mfma_f32_16x16x32_bf16(wreg[kt * NTW + nt], xf[kt],
                                                          acc[nt], 0, 0, 0);

    int grow = r0 + s * 16 + (l & 15);
    if (grow < n) {
      #pragma unroll
      for (int nt = 0; nt < NTW; ++nt) {
        int f0 = (w * NTW + nt) * 16 + hi * 4;
        float v0 = acc[nt][0], v1 = acc[nt][1], v2 = acc[nt][2], v3 = acc[nt][3];
        if (BIASRELU) {
          v0 = fmaxf(v0 + bb[nt].x, 0.0f);
          v1 = fmaxf(v1 + bb[nt].y, 0.0f);
          v2 = fmaxf(v2 + bb[nt].z, 0.0f);
          v3 = fmaxf(v3 + bb[nt].w, 0.0f);
        }
        if (OUTBF16) {
          ushort o[4];
          __hip_bfloat16 h;
          h = __float2bfloat16(v0); o[0] = *(ushort*)&h;
          h = __float2bfloat16(v1); o[1] = *(ushort*)&h;
          h = __float2bfloat16(v2); o[2] = *(ushort*)&h;
          h = __float2bfloat16(v3); o[3] = *(ushort*)&h;
          uint2 pk;
          pk.x = (uint)o[0] | ((uint)o[1] << 16);
          pk.y = (uint)o[2] | ((uint)o[3] << 16);
          *(uint2*)((ushort*)Cout + (size_t)grow * N + f0) = pk;
        } else {
          f32x4 pk = {v0, v1, v2, v3};
          *(f32x4*)((float*)Cout + (size_t)grow * N + f0) = pk;
        }
      }
    }
  }
}

// ---------------- GEMM3: bf16 [n,128] @ [128,2] -> [n,2], one wave per row ----------------

__global__ void k_gemm3(const ushort* __restrict__ A, const float* __restrict__ W3,
                        float* __restrict__ h3, int n) {
  int wavei = (int)((blockIdx.x * (size_t)blockDim.x + threadIdx.x) >> 6);
  int lane = threadIdx.x & 63;
  if (wavei >= n) return;
  uint u = *(const uint*)(A + (size_t)wavei * 128 + lane * 2);
  float x0 = __uint_as_float((u & 0xffffu) << 16);
  float x1 = __uint_as_float(u & 0xffff0000u);
  int k0 = lane * 2;
  float a0 = x0 * W3[k0 * 2 + 0] + x1 * W3[k0 * 2 + 2];
  float a1 = x0 * W3[k0 * 2 + 1] + x1 * W3[k0 * 2 + 3];
  #pragma unroll
  for (int d = 32; d >= 1; d >>= 1) {
    a0 += __shfl_xor(a0, d);
    a1 += __shfl_xor(a1, d);
  }
  if (lane == 0) {
    h3[(size_t)wavei * 2 + 0] = a0;
    h3[(size_t)wavei * 2 + 1] = a1;
  }
}

// ---------------- output ----------------

__global__ void k_fillout(float* __restrict__ out, int total) {
  int i = blockIdx.x * blockDim.x + threadIdx.x;
  if (i < total) out[i] = -0.69314718055994531f;
}

__global__ void k_agg3(const float* __restrict__ h3, const int* __restrict__ rp,
                       const int2* __restrict__ cw, const float* __restrict__ dis,
                       const float* __restrict__ b3, const int* __restrict__ l2g,
                       float* __restrict__ out, int n) {
  int i = blockIdx.x * blockDim.x + threadIdx.x;
  if (i >= n) return;
  float d2 = dis[i] * dis[i];
  float a0 = d2 * h3[(size_t)i * 2 + 0];
  float a1 = d2 * h3[(size_t)i * 2 + 1];
  int e0 = rp[i], e1 = rp[i + 1];
  for (int e = e0; e < e1; ++e) {
    int2 c = cw[e];
    float w = __int_as_float(c.y);
    a0 = fmaf(w, h3[(size_t)c.x * 2 + 0], a0);
    a1 = fmaf(w, h3[(size_t)c.x * 2 + 1], a1);
  }
  a0 += b3[0];
  a1 += b3[1];
  float m = fmaxf(a0, a1);
  float lse = m + logf(expf(a0 - m) + expf(a1 - m));
  int g = l2g[i];
  out[(size_t)g * 2 + 0] = a0 - lse;
  out[(size_t)g * 2 + 1] = a1 - lse;
}

// ---------------- launch ----------------

extern "C" void kernel_launch(void* const* d_in, const int* in_sizes, int n_in,
                              void* d_out, int out_size, void* d_ws, size_t ws_size,
                              hipStream_t stream) {
  const float* building_x = (const float*)d_in[0];
  const int*   l2g        = (const int*)d_in[1];
  const int*   esrc       = (const int*)d_in[2];
  const int*   edst       = (const int*)d_in[3];
  const float* W1 = (const float*)d_in[4];
  const float* b1 = (const float*)d_in[5];
  const float* W2 = (const float*)d_in[6];
  const float* b2 = (const float*)d_in[7];
  const float* W3 = (const float*)d_in[8];
  const float* b3 = (const float*)d_in[9];
  float* out = (float*)d_out;

  const int n_total = in_sizes[0] / F_IN;
  const int n_sub   = in_sizes[1];
  const int E       = in_sizes[2];
  const int nb      = (n_sub + 255) / 256;

  // ---- workspace (bf16 128-wide tensors, aliasing across phases) ----
  char* base = (char*)d_ws;
  auto al = [](size_t x) { return (x + 255) & ~(size_t)255; };
  size_t t128 = al((size_t)n_sub * 128 * 2);
  ushort* xsub = (ushort*)base;
  ushort* xt   = (ushort*)(base + t128);
  ushort* x1   = (ushort*)(base + 2 * t128);
  ushort* xt2  = xsub;
  ushort* h2b  = xt;
  size_t off = 2 * t128 + al((size_t)n_sub * 256 * 2);
  auto alloc = [&](size_t bytes) -> void* {
    void* p = base + off;
    off += al(bytes);
    return p;
  };
  float* h3   = (float*)alloc((size_t)n_sub * 2 * 4);
  int*   cnt  = (int*)alloc((size_t)n_sub * 4);
  int*   fill = (int*)alloc((size_t)n_sub * 4);
  int*   rp   = (int*)alloc((size_t)(n_sub + 1) * 4);
  float* dis  = (float*)alloc((size_t)n_sub * 4);
  int2*  cw   = (int2*)alloc((size_t)E * 8);
  int*   bsum = (int*)alloc((size_t)nb * 4);
  ushort* w1f = (ushort*)alloc((size_t)128 * 256 * 2);
  ushort* w2f = (ushort*)alloc((size_t)256 * 128 * 2);
  (void)ws_size; (void)n_in; (void)out_size;

  const int B = 256;

  // weight repack + input bf16 conversion (independent of CSR)
  k_prep_w<4, 16><<<16, 256, 0, stream>>>(W1, w1f);
  k_prep_w<8, 8><<<16, 256, 0, stream>>>(W2, w2f);
  k_tobf16<<<(n_sub * 32 + B - 1) / B, B, 0, stream>>>(building_x, l2g, xsub, n_sub);

  // CSR build
  k_zero<<<(n_sub + B - 1) / B, B, 0, stream>>>(cnt, n_sub);
  k_count<<<(E + B - 1) / B, B, 0, stream>>>(edst, cnt, E);
  k_scan1<<<nb, 256, 0, stream>>>(cnt, rp, bsum, dis, fill, n_sub);
  k_scan2<<<1, 1024, 0, stream>>>(bsum, nb);
  k_scan3<<<(n_sub + B - 1) / B, B, 0, stream>>>(rp, bsum, n_sub, E);
  k_fill_csr<<<(E + B - 1) / B, B, 0, stream>>>(esrc, edst, rp, fill, dis, cw, E);

  int aggBlocks  = (n_sub + 3) / 4;       // 4 waves / 256-thread block
  int gemmBlocks = (n_sub + 127) / 128;   // BM=128

  // Layer 1: aggregate (bf16 gather) -> bf16 xt, MFMA GEMM + bias + relu -> bf16 x1
  k_aggb<false><<<aggBlocks, B, 0, stream>>>(xsub, rp, cw, dis, nullptr, xt, n_sub);
  k_gemm_wspec<4, 4, true, true><<<gemmBlocks, 256, 0, stream>>>(xt, w1f, b1, x1, n_sub);

  // Layer 2: MFMA GEMM (x1 @ W2) -> bf16 h2b, aggregate + bias + relu -> bf16 xt2
  k_gemm_wspec<8, 2, true, false><<<gemmBlocks, 256, 0, stream>>>(x1, w2f, nullptr, h2b, n_sub);
  k_aggb<true><<<aggBlocks, B, 0, stream>>>(h2b, rp, cw, dis, b2, xt2, n_sub);

  // Layer 3: GEMM (2-wide), fill output, aggregate + bias + log_softmax scatter
  k_gemm3<<<aggBlocks, B, 0, stream>>>(xt2, W3, h3, n_sub);
  k_fillout<<<(2 * n_total + B - 1) / B, B, 0, stream>>>(out, 2 * n_total);
  k_agg3<<<(n_sub + B - 1) / B, B, 0, stream>>>(h3, rp, cw, dis, b3, l2g, out, n_sub);
}